// Round 2
// baseline (403.363 us; speedup 1.0000x reference)
//
#include <hip/hip_runtime.h>
#include <stdint.h>

// Disable FMA contraction file-wide: we must replicate the reference's
// per-op f32 rounding (decode + IoU) to avoid NMS decision flips.
#pragma clang fp contract(off)

#define B_IMGS   4
#define NLVL     5
#define A_TOTAL  242991
#define NSEL     4741          // 1000*4 + 741
#define NBUCK    8192          // 13-bit buckets: sign+exp+4 mantissa (os>>19)
#define BSHIFT   19
#define CAND_CAP 2048
#define POST_NMS 1000
#define NBL      (B_IMGS * NLVL)
#define NMS_TH   0.7f
#define NEGV     (-1e10f)
#define W_IMGF   1216.0f
#define H_IMGF   800.0f
#define MIN_SZ   1e-3f
#define BBOX_CLIP 4.135166556742356f   // log(1000/16)

// Fused-kernel geometry: 20 blocks (= B*NLVL) x 1024 threads. 20 <= 256 CUs
// -> co-residency trivially guaranteed; grid barrier fence traffic is 20
// workgroups, not 136 (round-1's ~16us/barrier fence storm).
#define NBLK     NBL
#define BLKT     1024

// ---------- level helpers ----------
__device__ __forceinline__ int lvl_k(int l) { return (l == 4) ? 741 : 1000; }
__device__ __forceinline__ void lvl_span(int l, int& lstart, int& n) {
    switch (l) {
    case 0: lstart = 0;      n = 182400; break;
    case 1: lstart = 182400; n = 45600;  break;
    case 2: lstart = 228000; n = 11400;  break;
    case 3: lstart = 239400; n = 2850;   break;
    default:lstart = 242250; n = 741;    break;
    }
}

// ---------- order-preserving float<->uint ----------
__device__ __forceinline__ unsigned flipf(float f) {
    unsigned u = __float_as_uint(f);
    return u ^ (unsigned)(((int)u >> 31) | 0x80000000);
}
__device__ __forceinline__ float unflipf(unsigned os) {
    unsigned u = (os & 0x80000000u) ? (os ^ 0x80000000u) : ~os;
    return __uint_as_float(u);
}

// ---------- binary search in LDS: #elements < key ----------
__device__ __forceinline__ int lbound_lds(const unsigned long long* s, int len,
                                          unsigned long long key) {
    int lo = 0, hi = len;
    while (lo < hi) {
        int mid = (lo + hi) >> 1;
        if (s[mid] < key) lo = mid + 1; else hi = mid;
    }
    return lo;
}

// ---------- grid barrier (monotonic counter; agent-scope fences handle
// cross-XCD L2 non-coherence). Only 20 arrivals -> cheap. ----------
__device__ __forceinline__ void gbar(unsigned* bar, unsigned target) {
    __syncthreads();                       // all waves' stores drained (vmcnt)
    if (threadIdx.x == 0) {
        __threadfence();                   // agent release: writeback L2
        __hip_atomic_fetch_add(bar, 1u, __ATOMIC_RELAXED, __HIP_MEMORY_SCOPE_AGENT);
        while (__hip_atomic_load(bar, __ATOMIC_RELAXED, __HIP_MEMORY_SCOPE_AGENT) < target)
            __builtin_amdgcn_s_sleep(2);
        __threadfence();                   // agent acquire: invalidate L1/L2
    }
    __syncthreads();
}

// ---------- workspace layout (hist/cand/mask now live in LDS only) ----------
static constexpr size_t OFF_BOXMAX = 0;                                    // 16 B
static constexpr size_t OFF_BAR    = 16;                                   // 4 B
static constexpr size_t ZERO_BYTES = 32;
static constexpr size_t OFF_SEL    = 32;
static constexpr size_t OFF_BOXR   = OFF_SEL  + (size_t)B_IMGS * NSEL * 8;
static constexpr size_t OFF_SCR    = OFF_BOXR + (size_t)B_IMGS * NSEL * 16;
static constexpr size_t OFF_BOXL   = OFF_SCR  + (size_t)B_IMGS * NSEL * 4;
static constexpr size_t OFF_VAL    = OFF_BOXL + (size_t)B_IMGS * NSEL * 16;
static constexpr size_t OFF_RMAP   = OFF_VAL  + (size_t)B_IMGS * NSEL * 4;
static constexpr size_t OFF_KEEP   = OFF_RMAP + (size_t)B_IMGS * NSEL * 4;
static constexpr size_t WS_NEED    = OFF_KEEP + (size_t)B_IMGS * NSEL * 4; // ~1.1 MB

// ---------- LDS layout (union across phases; max 50,368 B < 64 KB static) ----------
#define S_LH     0          // u32[8192]  = 32768   (ABC hist)
#define S_SBUF   32768      // u64[2048]  = 16384   (ABC cand keys / sort)
#define S_PART   49152      // u32[256]
#define S_CHB    50176      // u32[32]
#define S_SCAL   50304      // 4 ints
#define S_SKEY   0          // u64[4741]  = 37928   (D)
#define S_WMAX   37952      // f32[16]              (D)
#define S_BOX5   0          // f32[1024][5] = 20480 (EF)
#define S_TILEA  20480      // u64[64*16] = 8192    (EF)
#define S_TILEB  28672      // u64[64*16] = 8192    (EF)
#define S_PS     0          // i32[1024]            (G)
#define SMEM_SZ  50368

// ---------- EF: compute one 64-row x 16-window mask tile into LDS ----------
// Called by waves 1..15; wave q covers windows {q-1, q+14} (>= cc).
// Float op order identical to the verified k_mask.
__device__ __forceinline__ void ef_tile(const float (*boxes5)[5],
                                        unsigned long long* buf,
                                        int cc, int kl, int wave, int lane) {
    const int rbase = cc << 6;
    const int i = rbase + lane;
    float ix1 = 0.f, iy1 = 0.f, ix2 = 0.f, iy2 = 0.f, ai = 0.f;
    const bool row_on = (i < kl);
    if (row_on) {
        ix1 = boxes5[i][0]; iy1 = boxes5[i][1];
        ix2 = boxes5[i][2]; iy2 = boxes5[i][3]; ai = boxes5[i][4];
    }
    for (int w = wave - 1; w < 16; w += 15) {
        if (w < cc) continue;
        const int j0 = w << 6;
        const int jmax = min(64, kl - j0);
        unsigned long long word = 0;
        if (row_on && jmax > 0) {
            for (int bb = 0; bb < jmax; ++bb) {
                int jj = j0 + bb;
                if (jj <= i) continue;
                float ltx = fmaxf(ix1, boxes5[jj][0]), lty = fmaxf(iy1, boxes5[jj][1]);
                float rbx = fminf(ix2, boxes5[jj][2]), rby = fminf(iy2, boxes5[jj][3]);
                float ww = fmaxf(rbx - ltx, 0.0f), hh = fmaxf(rby - lty, 0.0f);
                float inter = ww * hh;
                float iou = inter / ((ai + boxes5[jj][4]) - inter);  // NaN>th == false
                if (iou > NMS_TH) word |= (1ULL << bb);
            }
        }
        buf[(lane << 4) + w] = word;
    }
}

// ---------- the fused pipeline ----------
// ABC (per-bl: hist+threshold+compact+sort, all in LDS) -> gbar
// D   (decode+clip+rank, 5 blocks/image)                -> gbar
// EF  (per-bl: mask tiles in LDS, pipelined with serial greedy resolve) -> gbar
// G   (compact kept entries into output, 4 blocks)
__global__ __launch_bounds__(BLKT) void k_fused(
    const float* __restrict__ obj, const float* __restrict__ deltas,
    const float* __restrict__ anchors,
    unsigned* __restrict__ boxmax, unsigned* __restrict__ bar,
    unsigned long long* __restrict__ sel,
    float* __restrict__ boxes_r, float* __restrict__ score_r,
    float* __restrict__ boxes_l, int* __restrict__ valid_l,
    int* __restrict__ rankmap, int* __restrict__ keep_r,
    float* __restrict__ out)
{
    __shared__ __align__(16) char smem[SMEM_SZ];
    const int tid  = threadIdx.x;
    const int bid  = blockIdx.x;
    const int lane = tid & 63;
    const int wave = tid >> 6;

    // ============ Phase ABC: per-(b,level) topk entirely in-block ============
    {
        unsigned* lh            = (unsigned*)(smem + S_LH);
        unsigned long long* sbf = (unsigned long long*)(smem + S_SBUF);
        unsigned* part          = (unsigned*)(smem + S_PART);
        unsigned* chb           = (unsigned*)(smem + S_CHB);
        int*      s_chunk       = (int*)     (smem + S_SCAL);
        unsigned* s_cum         = (unsigned*)(smem + S_SCAL + 4);
        unsigned* s_thr         = (unsigned*)(smem + S_SCAL + 8);
        unsigned* lcnt          = (unsigned*)(smem + S_SCAL + 12);
        const int b = bid / NLVL, l = bid % NLVL;
        int lstart, n;
        lvl_span(l, lstart, n);
        const int kl = lvl_k(l);
        for (int i = tid; i < NBUCK; i += BLKT) lh[i] = 0;
        if (tid == 0) *lcnt = 0;
        __syncthreads();
        const float* src = obj + (size_t)b * A_TOTAL + lstart;
        for (int i = tid; i < n; i += BLKT)
            atomicAdd(&lh[flipf(src[i]) >> BSHIFT], 1u);
        __syncthreads();
        if (tid < 256) {
            unsigned s = 0;
            for (int i = 0; i < 32; ++i) s += lh[tid * 32 + i];
            part[tid] = s;
        }
        __syncthreads();
        if (tid == 0) {
            unsigned cum = 0;
            int t = 255;
            for (; t > 0; --t) {
                if (cum + part[t] >= (unsigned)kl) break;
                cum += part[t];
            }
            *s_chunk = t;
            *s_cum = cum;
        }
        __syncthreads();
        if (tid < 32) chb[tid] = lh[(*s_chunk) * 32 + tid];
        __syncthreads();
        if (tid == 0) {
            unsigned c2 = *s_cum;
            int T = (*s_chunk) * 32;
            for (int i = 31; i >= 0; --i) {
                c2 += chb[i];
                if (c2 >= (unsigned)kl) { T = (*s_chunk) * 32 + i; break; }
            }
            *s_thr = (unsigned)T;
        }
        __syncthreads();
        const unsigned T = *s_thr;
        for (int i = tid; i < n; i += BLKT) {
            unsigned os = flipf(src[i]);
            if ((os >> BSHIFT) >= T) {
                unsigned slot = atomicAdd(lcnt, 1u);
                if (slot < CAND_CAP)
                    sbf[slot] = (((unsigned long long)(~os)) << 32) | (unsigned)(lstart + i);
            }
        }
        __syncthreads();
        unsigned m = *lcnt; if (m > CAND_CAP) m = CAND_CAP;
        for (int i = tid; i < CAND_CAP; i += BLKT)
            if ((unsigned)i >= m) sbf[i] = ~0ULL;
        __syncthreads();
        // bitonic sort, 1024 threads = exactly one compare-swap per pass
        for (int k = 2; k <= CAND_CAP; k <<= 1) {
            for (int j = k >> 1; j > 0; j >>= 1) {
                int i = ((tid / j) * (j << 1)) + (tid % j);
                int p = i + j;
                bool up = ((i & k) == 0);
                unsigned long long a = sbf[i], c = sbf[p];
                if ((a > c) == up) { sbf[i] = c; sbf[p] = a; }
                __syncthreads();
            }
        }
        for (int q = tid; q < kl; q += BLKT)
            sel[(size_t)b * NSEL + l * 1000 + q] = sbf[q];
    }
    gbar(bar, 1u * NBLK);

    // ============ Phase D: decode + clip + global rank (5 blocks/image) ============
    {
        unsigned long long* skey = (unsigned long long*)(smem + S_SKEY);
        float* wmax = (float*)(smem + S_WMAX);
        const int b = bid / 5;
        const int sub = bid % 5;
        for (int i = tid; i < NSEL; i += BLKT)
            skey[i] = sel[(size_t)b * NSEL + i];
        __syncthreads();

        int p = sub * BLKT + tid;
        bool on = p < NSEL;
        float mx = 0.0f;
        if (on) {
            int l = p / 1000;           // p in [4000,4741) -> 4
            int q = p - l * 1000;
            unsigned long long key = skey[p];
            unsigned a = (unsigned)(key & 0xFFFFFFFFu);
            unsigned os = ~((unsigned)(key >> 32));
            if (a >= A_TOTAL) a = 0;    // impossible-path safety
            float score = unflipf(os);
            int r = q;
            for (int l2 = 0; l2 < NLVL; ++l2) {
                if (l2 == l) continue;
                r += lbound_lds(skey + l2 * 1000, lvl_k(l2), key);
            }
            const float* dv = deltas + ((size_t)b * A_TOTAL + a) * 4;
            const float* av = anchors + (size_t)a * 4;
            float ax1 = av[0], ay1 = av[1], ax2 = av[2], ay2 = av[3];
            float wa = ax2 - ax1, ha = ay2 - ay1;
            float cxa = ax1 + 0.5f * wa, cya = ay1 + 0.5f * ha;
            float dx = dv[0], dy = dv[1];
            float dw = fminf(dv[2], BBOX_CLIP), dh = fminf(dv[3], BBOX_CLIP);
            float cx = dx * wa + cxa, cy = dy * ha + cya;
            float w = expf(dw) * wa, h = expf(dh) * ha;
            float x1 = cx - 0.5f * w, y1 = cy - 0.5f * h;
            float x2 = cx + 0.5f * w, y2 = cy + 0.5f * h;
            float x1c = fminf(fmaxf(x1, 0.0f), W_IMGF);
            float y1c = fminf(fmaxf(y1, 0.0f), H_IMGF);
            float x2c = fminf(fmaxf(x2, 0.0f), W_IMGF);
            float y2c = fminf(fmaxf(y2, 0.0f), H_IMGF);
            int valid = ((x2c - x1c) >= MIN_SZ) && ((y2c - y1c) >= MIN_SZ);
            mx = fmaxf(fmaxf(x1c, y1c), fmaxf(x2c, y2c));
            size_t rp = (size_t)b * NSEL + r;
            boxes_r[rp * 4 + 0] = x1c; boxes_r[rp * 4 + 1] = y1c;
            boxes_r[rp * 4 + 2] = x2c; boxes_r[rp * 4 + 3] = y2c;
            score_r[rp] = score;
            size_t pp = (size_t)b * NSEL + p;
            boxes_l[pp * 4 + 0] = x1c; boxes_l[pp * 4 + 1] = y1c;
            boxes_l[pp * 4 + 2] = x2c; boxes_l[pp * 4 + 3] = y2c;
            valid_l[pp] = valid;
            rankmap[pp] = r;
        }
        #pragma unroll
        for (int o = 32; o > 0; o >>= 1)
            mx = fmaxf(mx, __shfl_xor(mx, o));
        if ((tid & 63) == 0) wmax[tid >> 6] = mx;
        __syncthreads();
        if (tid == 0) {
            float m2 = wmax[0];
            #pragma unroll
            for (int i = 1; i < 16; ++i) m2 = fmaxf(m2, wmax[i]);
            atomicMax(boxmax + b, __float_as_uint(m2));
        }
    }
    gbar(bar, 2u * NBLK);

    // ============ Phase EF: mask tiles (waves 1..15) || greedy resolve (wave 0) ============
    {
        float (*boxes5)[5]        = (float(*)[5])(smem + S_BOX5);
        unsigned long long* tileA = (unsigned long long*)(smem + S_TILEA);
        unsigned long long* tileB = (unsigned long long*)(smem + S_TILEB);
        const int b = bid / NLVL, l = bid % NLVL;
        const int kl = lvl_k(l);
        const int nch = (kl + 63) >> 6;          // 16 or 12
        const int base = b * NSEL + l * 1000;
        const float M = __uint_as_float(boxmax[b]) + 1.0f;
        const float off = (float)l * M;

        // stage all level boxes (offset-added) + areas into LDS
        if (tid < kl) {
            const float* bp = boxes_l + ((size_t)base + tid) * 4;
            float x1 = bp[0] + off, y1 = bp[1] + off;
            float x2 = bp[2] + off, y2 = bp[3] + off;
            boxes5[tid][0] = x1; boxes5[tid][1] = y1;
            boxes5[tid][2] = x2; boxes5[tid][3] = y2;
            boxes5[tid][4] = (x2 - x1) * (y2 - y1);
        } else {
            boxes5[tid][0] = 0.f; boxes5[tid][1] = 0.f;
            boxes5[tid][2] = 0.f; boxes5[tid][3] = 0.f; boxes5[tid][4] = 0.f;
        }
        unsigned long long keep_w = 0;
        __syncthreads();

        // prologue: wave0 gathers keep bits; waves 1..15 compute tile 0
        if (wave == 0) {
            for (int c2 = 0; c2 < 16; ++c2) {
                int q = (c2 << 6) + lane;
                int vv = (q < kl) ? valid_l[base + q] : 0;
                unsigned long long bm = __ballot(vv);
                if (lane == c2) keep_w = bm;
            }
        } else {
            ef_tile(boxes5, tileA, 0, kl, wave, lane);
        }
        __syncthreads();

        for (int c = 0; c < nch; ++c) {
            unsigned long long* cur = (c & 1) ? tileB : tileA;
            unsigned long long* nxt = (c & 1) ? tileA : tileB;
            if (wave > 0) {
                if (c + 1 < nch) ef_tile(boxes5, nxt, c + 1, kl, wave, lane);
            } else {
                unsigned long long kw = __shfl(keep_w, c);   // uniform
                if (kw) {
                    // within-chunk greedy closure (serial over nonzero-diag rows)
                    unsigned long long diag = cur[(lane << 4) + c];
                    unsigned dlo = (unsigned)diag, dhi = (unsigned)(diag >> 32);
                    unsigned long long nz = __ballot(diag != 0ULL);
                    unsigned long long rem = kw & nz;
                    while (rem) {
                        int rr = __ffsll((long long)rem) - 1;
                        unsigned lo = __builtin_amdgcn_readlane(dlo, rr);
                        unsigned hi = __builtin_amdgcn_readlane(dhi, rr);
                        unsigned long long d = ((unsigned long long)hi << 32) | lo;
                        kw &= ~d;
                        rem &= ~(d | (1ULL << rr));
                    }
                    // batched cross-chunk suppression
                    unsigned long long supp = 0;
                    if (lane < 16) {
                        #pragma unroll
                        for (int rr = 0; rr < 64; ++rr) {
                            unsigned long long mm = cur[(rr << 4) + lane];
                            supp |= (((kw >> rr) & 1ULL) ? mm : 0ULL);
                        }
                    }
                    if (lane == c) keep_w = kw;
                    else if (lane < 16 && lane > c) keep_w &= ~supp;
                }
            }
            __syncthreads();
        }
        // scatter keep bits to global-rank order
        if (wave == 0) {
            for (int c2 = 0; c2 < 16; ++c2) {
                unsigned long long kwc = __shfl(keep_w, c2);
                int q = (c2 << 6) + lane;
                if (q < kl)
                    keep_r[b * NSEL + rankmap[base + q]] = (int)((kwc >> lane) & 1ULL);
            }
        }
    }
    gbar(bar, 3u * NBLK);

    // ============ Phase G: compact kept entries (score order) into output ============
    if (bid < B_IMGS) {
        int* ps = (int*)(smem + S_PS);
        const int b = bid;
        float* ob = out + (size_t)b * POST_NMS * 4;
        float* osc = out + (size_t)B_IMGS * POST_NMS * 4 + (size_t)b * POST_NMS;
        for (int p = tid; p < POST_NMS; p += BLKT) {
            ob[p * 4 + 0] = 0.0f; ob[p * 4 + 1] = 0.0f;
            ob[p * 4 + 2] = 0.0f; ob[p * 4 + 3] = 0.0f;
            osc[p] = NEGV;
        }
        __syncthreads();
        const int CH = 5;  // 5*1024 = 5120 >= 4741
        int basei = tid * CH;
        int c0 = 0;
        #pragma unroll
        for (int k = 0; k < CH; ++k) {
            int rr = basei + k;
            if (rr < NSEL) c0 += keep_r[b * NSEL + rr];
        }
        ps[tid] = c0;
        __syncthreads();
        for (int ofs = 1; ofs < BLKT; ofs <<= 1) {
            int v = (tid >= ofs) ? ps[tid - ofs] : 0;
            __syncthreads();
            ps[tid] += v;
            __syncthreads();
        }
        int p = ps[tid] - c0;   // exclusive prefix
        #pragma unroll
        for (int k = 0; k < CH; ++k) {
            int rr = basei + k;
            if (rr < NSEL && keep_r[b * NSEL + rr]) {
                if (p < POST_NMS) {
                    const float* bp = boxes_r + ((size_t)b * NSEL + rr) * 4;
                    ob[p * 4 + 0] = bp[0]; ob[p * 4 + 1] = bp[1];
                    ob[p * 4 + 2] = bp[2]; ob[p * 4 + 3] = bp[3];
                    osc[p] = score_r[(size_t)b * NSEL + rr];
                }
                ++p;
            }
        }
    }
}

extern "C" void kernel_launch(void* const* d_in, const int* in_sizes, int n_in,
                              void* d_out, int out_size, void* d_ws, size_t ws_size,
                              hipStream_t stream) {
    const float* obj     = (const float*)d_in[0];   // [4, 242991]
    const float* deltas  = (const float*)d_in[1];   // [4, 242991, 4]
    const float* anchors = (const float*)d_in[2];   // [242991, 4]
    float* out = (float*)d_out;                     // [4,1000,4] ++ [4,1000]

    char* ws = (char*)d_ws;
    unsigned*            boxmax  = (unsigned*)(ws + OFF_BOXMAX);
    unsigned*            bar     = (unsigned*)(ws + OFF_BAR);
    unsigned long long*  sel     = (unsigned long long*)(ws + OFF_SEL);
    float*               boxes_r = (float*)(ws + OFF_BOXR);
    float*               score_r = (float*)(ws + OFF_SCR);
    float*               boxes_l = (float*)(ws + OFF_BOXL);
    int*                 valid_l = (int*)(ws + OFF_VAL);
    int*                 rankmap = (int*)(ws + OFF_RMAP);
    int*                 keep_r  = (int*)(ws + OFF_KEEP);

    (void)in_sizes; (void)n_in; (void)out_size; (void)ws_size; (void)WS_NEED;

    // zero boxmax + barrier counter only (ws is poisoned 0xAA before every call)
    hipMemsetAsync(d_ws, 0, ZERO_BYTES, stream);

    k_fused<<<NBLK, BLKT, 0, stream>>>(
        obj, deltas, anchors, boxmax, bar, sel,
        boxes_r, score_r, boxes_l, valid_l, rankmap, keep_r, out);
}

// Round 3
// 183.343 us; speedup vs baseline: 2.2001x; 2.2001x over previous
//
#include <hip/hip_runtime.h>
#include <stdint.h>

// Disable FMA contraction file-wide: we must replicate the reference's
// per-op f32 rounding (decode + IoU) to avoid NMS decision flips.
#pragma clang fp contract(off)

#define B_IMGS   4
#define NLVL     5
#define A_TOTAL  242991
#define NSEL     4741          // 1000*4 + 741
#define NBUCK    8192          // 13-bit buckets: sign+exp+4 mantissa (os>>19)
#define BSHIFT   19
#define CAND_CAP 2048
#define POST_NMS 1000
#define NBL      (B_IMGS * NLVL)
#define NMS_TH   0.7f
#define NEGV     (-1e10f)
#define W_IMGF   1216.0f
#define H_IMGF   800.0f
#define MIN_SZ   1e-3f
#define BBOX_CLIP 4.135166556742356f   // log(1000/16), rounded to f32 by compiler

// ---------- level helpers ----------
__device__ __forceinline__ int lvl_k(int l) { return (l == 4) ? 741 : 1000; }

// ---------- order-preserving float<->uint ----------
__device__ __forceinline__ unsigned flipf(float f) {
    unsigned u = __float_as_uint(f);
    return u ^ (unsigned)(((int)u >> 31) | 0x80000000);
}
__device__ __forceinline__ float unflipf(unsigned os) {
    unsigned u = (os & 0x80000000u) ? (os ^ 0x80000000u) : ~os;
    return __uint_as_float(u);
}

// ---------- async global->LDS DMA (16B per lane, wave-uniform LDS base) ----------
__device__ __forceinline__ void async_cp16(const void* g, void* l) {
    __builtin_amdgcn_global_load_lds(
        (const __attribute__((address_space(1))) unsigned*)g,
        (__attribute__((address_space(3))) unsigned*)l,
        16, 0, 0);
}

// ---------- workspace layout ----------
static constexpr size_t SZ_HIST    = (size_t)NBL * NBUCK * sizeof(unsigned);        // 655,360
static constexpr size_t OFF_CNT    = SZ_HIST;                                        // +80
static constexpr size_t OFF_BOXMAX = OFF_CNT + NBL * sizeof(unsigned);               // +16
static constexpr size_t ZERO_BYTES = OFF_BOXMAX + B_IMGS * sizeof(unsigned);
static constexpr size_t OFF_CAND   = (ZERO_BYTES + 15) & ~(size_t)15;
static constexpr size_t OFF_SEL    = OFF_CAND + (size_t)NBL * CAND_CAP * 8;
static constexpr size_t OFF_BOXR   = OFF_SEL + (size_t)B_IMGS * NSEL * 8;
static constexpr size_t OFF_SCR    = OFF_BOXR + (size_t)B_IMGS * NSEL * 16;
static constexpr size_t OFF_BOXL   = OFF_SCR + (size_t)B_IMGS * NSEL * 4;
static constexpr size_t OFF_VAL    = OFF_BOXL + (size_t)B_IMGS * NSEL * 16;
static constexpr size_t OFF_RMAP   = OFF_VAL + (size_t)B_IMGS * NSEL * 4;
static constexpr size_t OFF_KEEP   = OFF_RMAP + (size_t)B_IMGS * NSEL * 4;
static constexpr size_t OFF_MASK   = OFF_KEEP + (size_t)B_IMGS * NSEL * 4;           // 16-aligned
static constexpr size_t WS_NEED    = OFF_MASK + (size_t)NBL * 1024 * 16 * 8;         // ~4.7 MB

// ---------- K1: per-(b,level) LDS histogram, merged to global ----------
// 34 blocks per image, 512 threads, each covering one (level, sub-chunk) span.
#define HBLK_PER_IMG 34
__global__ void k_hist(const float* __restrict__ obj, unsigned* __restrict__ hist) {
    __shared__ unsigned lh[NBUCK];   // 32 KB
    const int tid = threadIdx.x;     // 512
    const int b = blockIdx.x / HBLK_PER_IMG;
    const int r = blockIdx.x - b * HBLK_PER_IMG;
    int l, sub, chunk, lstart, n;
    if (r < 24)      { l = 0; sub = r;      chunk = 7600; lstart = 0;      n = 182400; }
    else if (r < 30) { l = 1; sub = r - 24; chunk = 7600; lstart = 182400; n = 45600; }
    else if (r < 32) { l = 2; sub = r - 30; chunk = 5700; lstart = 228000; n = 11400; }
    else if (r == 32){ l = 3; sub = 0;      chunk = 2850; lstart = 239400; n = 2850; }
    else             { l = 4; sub = 0;      chunk = 741;  lstart = 242250; n = 741; }
    #pragma unroll
    for (int i = tid; i < NBUCK; i += 512) lh[i] = 0;
    __syncthreads();
    const int s0 = sub * chunk;
    const int cnt = min(chunk, n - s0);
    const float* src = obj + (size_t)b * A_TOTAL + lstart + s0;
    for (int i = tid; i < cnt; i += 512) {
        unsigned os = flipf(src[i]);
        atomicAdd(&lh[os >> BSHIFT], 1u);
    }
    __syncthreads();
    unsigned* gh = hist + (size_t)(b * NLVL + l) * NBUCK;
    for (int i = tid; i < NBUCK; i += 512) {
        unsigned v = lh[i];
        if (v) atomicAdd(&gh[i], v);
    }
}

// ---------- K2: compact candidates (threshold scan fused in-prologue) ----------
// One (b,level,sub-span) per block. Each block redundantly computes its bl's
// threshold from the global histogram (written by the PREVIOUS kernel ->
// kernel-boundary visibility). Threshold located via wave-parallel suffix
// scan (shfl_up + ballot) instead of a tid==0 serial LDS-latency loop.
#define CBLK_PER_IMG 65
__global__ void k_compact(const float* __restrict__ obj, const unsigned* __restrict__ hist,
                          unsigned* __restrict__ cnt, unsigned long long* __restrict__ cand) {
    __shared__ unsigned long long sbuf[CAND_CAP];   // 16 KB staging
    __shared__ unsigned part[256];
    __shared__ unsigned wsum[4];
    __shared__ unsigned fcnt[4];
    __shared__ unsigned s_cum, s_thr, lcnt, gbase;
    const int tid = threadIdx.x;     // 256
    const int b = blockIdx.x / CBLK_PER_IMG;
    const int r = blockIdx.x - b * CBLK_PER_IMG;
    int l, sub, chunk, lstart, n;
    if (r < 48)      { l = 0; sub = r;      chunk = 3800; lstart = 0;      n = 182400; }
    else if (r < 60) { l = 1; sub = r - 48; chunk = 3800; lstart = 182400; n = 45600; }
    else if (r < 63) { l = 2; sub = r - 60; chunk = 3800; lstart = 228000; n = 11400; }
    else if (r == 63){ l = 3; sub = 0;      chunk = 2850; lstart = 239400; n = 2850; }
    else             { l = 4; sub = 0;      chunk = 741;  lstart = 242250; n = 741; }
    const int bl = b * NLVL + l;
    const int kl = lvl_k(l);
    // ---- threshold scan (identical result in all blocks of this bl) ----
    const unsigned* h = hist + (size_t)bl * NBUCK;
    {
        unsigned s = 0;
        for (int i = 0; i < 32; ++i) s += h[tid * 32 + i];
        part[tid] = s;
    }
    if (tid == 0) { lcnt = 0; s_cum = 0; }
    __syncthreads();
    // Stage 1: suffix(t) = sum_{u>=t} part[u] for t = 255 - tid, via
    // inclusive prefix scan of reversed part[] across the 4 waves.
    const int lane = tid & 63, wv = tid >> 6;
    unsigned x = part[255 - tid];
    #pragma unroll
    for (int d = 1; d < 64; d <<= 1) {
        unsigned up = __shfl_up(x, d);
        if (lane >= d) x += up;
    }
    if (lane == 63) wsum[wv] = x;
    __syncthreads();
    unsigned add = 0;
    #pragma unroll
    for (int u = 0; u < 3; ++u) if (u < wv) add += wsum[u];
    const unsigned suffix = x + add;   // suffix(255 - tid)
    // suffix is non-increasing in t -> flags {suffix(t) >= kl} form a prefix
    // in t; chunk = (#flags) - 1 (serial loop's break index, verified equal).
    unsigned long long bm = __ballot(suffix >= (unsigned)kl);
    if (lane == 0) fcnt[wv] = (unsigned)__popcll(bm);
    __syncthreads();
    const int chnk = (int)(fcnt[0] + fcnt[1] + fcnt[2] + fcnt[3]) - 1;
    if ((255 - tid) == chnk + 1) s_cum = suffix;   // = suffix(chunk+1); 0 if chunk==255
    __syncthreads();
    // Stage 2 (wave 0 only): within the 32 buckets of chnk, find largest
    // bucket i with s_cum + sum_{u>=i} chb[u] >= kl.
    if (wv == 0) {
        unsigned y = (lane < 32) ? h[chnk * 32 + (31 - lane)] : 0u;
        #pragma unroll
        for (int d = 1; d < 32; d <<= 1) {
            unsigned up = __shfl_up(y, d);
            if (lane >= d) y += up;
        }
        unsigned suf2 = s_cum + y;     // bucket i = 31 - lane (lane < 32)
        unsigned long long bm2 = __ballot((lane < 32) && (suf2 >= (unsigned)kl));
        if (lane == 0) {
            int istar = (int)__popcll(bm2) - 1;   // monotone -> count-1
            s_thr = (unsigned)(chnk * 32 + istar);
        }
    }
    __syncthreads();
    const unsigned T = s_thr;
    // ---- pass filter into LDS staging ----
    const int s0 = sub * chunk;
    const int m = min(chunk, n - s0);
    const int abase = lstart + s0;
    const float* src = obj + (size_t)b * A_TOTAL + abase;
    for (int i = tid; i < m; i += 256) {
        unsigned os = flipf(src[i]);
        if ((os >> BSHIFT) >= T) {
            unsigned slot = atomicAdd(&lcnt, 1u);
            if (slot < CAND_CAP)
                sbuf[slot] = (((unsigned long long)(~os)) << 32) | (unsigned)(abase + i);
        }
    }
    __syncthreads();
    unsigned total = lcnt; if (total > CAND_CAP) total = CAND_CAP;
    if (tid == 0) gbase = atomicAdd(&cnt[bl], total);
    __syncthreads();
    const unsigned gb = gbase;
    for (unsigned i = tid; i < total; i += 256) {
        unsigned g = gb + i;
        if (g < CAND_CAP)
            cand[(size_t)bl * CAND_CAP + g] = sbuf[i];
    }
}

// ---------- K3: per-(b,level) bitonic sort of candidates; keep top-k ----------
// 1024 threads: exactly one compare-swap per thread per pass.
__global__ void k_sortlevel(const unsigned long long* __restrict__ cand,
                            const unsigned* __restrict__ cnt,
                            unsigned long long* __restrict__ sel) {
    __shared__ unsigned long long keys[CAND_CAP];
    const int bl = blockIdx.x;
    const int b = bl / NLVL, l = bl - (bl / NLVL) * NLVL;
    const int tid = threadIdx.x;     // 1024
    int m = (int)cnt[bl];
    if (m > CAND_CAP) m = CAND_CAP;
    for (int i = tid; i < CAND_CAP; i += 1024)
        keys[i] = (i < m) ? cand[(size_t)bl * CAND_CAP + i] : ~0ULL;
    __syncthreads();
    for (int k = 2; k <= CAND_CAP; k <<= 1) {
        for (int j = k >> 1; j > 0; j >>= 1) {
            int i = ((tid / j) * (j << 1)) + (tid % j);
            int p = i + j;
            bool up = ((i & k) == 0);
            unsigned long long a = keys[i], c = keys[p];
            if ((a > c) == up) { keys[i] = c; keys[p] = a; }
            __syncthreads();
        }
    }
    int kl = lvl_k(l);
    for (int q = tid; q < kl; q += 1024)
        sel[(size_t)b * NSEL + l * 1000 + q] = keys[q];
}

// ---------- binary search in LDS: #elements < key ----------
__device__ __forceinline__ int lbound_lds(const unsigned long long* s, int len,
                                          unsigned long long key) {
    int lo = 0, hi = len;
    while (lo < hi) {
        int mid = (lo + hi) >> 1;
        if (s[mid] < key) lo = mid + 1; else hi = mid;
    }
    return lo;
}

// ---------- K4: decode+clip+valid; global rank via LDS 5-way merge-rank ----------
// grid (5, b) x 1024 threads — skey staged once per 1024 entries.
__global__ void k_decode(const float* __restrict__ deltas, const float* __restrict__ anchors,
                         const unsigned long long* __restrict__ sel,
                         float* __restrict__ boxes_r, float* __restrict__ score_r,
                         float* __restrict__ boxes_l, int* __restrict__ valid_l,
                         int* __restrict__ rankmap, unsigned* __restrict__ boxmax) {
    __shared__ unsigned long long skey[NSEL];     // 37,928 B
    __shared__ float wmax[16];
    const int b = blockIdx.y;
    const int tid = threadIdx.x;                  // 1024
    for (int i = tid; i < NSEL; i += 1024)
        skey[i] = sel[(size_t)b * NSEL + i];
    __syncthreads();

    int p = blockIdx.x * 1024 + tid;
    bool on = p < NSEL;
    float mx = 0.0f;
    if (on) {
        int l = p / 1000;           // p in [4000,4741) -> 4
        int q = p - l * 1000;
        unsigned long long key = skey[p];
        unsigned a = (unsigned)(key & 0xFFFFFFFFu);
        unsigned os = ~((unsigned)(key >> 32));
        if (a >= A_TOTAL) a = 0;    // impossible-path safety (MAX padding)
        float score = unflipf(os);
        // global rank = q + sum over other levels of (#keys < key)
        int r = q;
        for (int l2 = 0; l2 < NLVL; ++l2) {
            if (l2 == l) continue;
            r += lbound_lds(skey + l2 * 1000, lvl_k(l2), key);
        }
        // decode (replicates reference op order; contraction disabled)
        const float* dv = deltas + ((size_t)b * A_TOTAL + a) * 4;
        const float* av = anchors + (size_t)a * 4;
        float ax1 = av[0], ay1 = av[1], ax2 = av[2], ay2 = av[3];
        float wa = ax2 - ax1, ha = ay2 - ay1;
        float cxa = ax1 + 0.5f * wa, cya = ay1 + 0.5f * ha;
        float dx = dv[0], dy = dv[1];
        float dw = fminf(dv[2], BBOX_CLIP), dh = fminf(dv[3], BBOX_CLIP);
        float cx = dx * wa + cxa, cy = dy * ha + cya;
        float w = expf(dw) * wa, h = expf(dh) * ha;
        float x1 = cx - 0.5f * w, y1 = cy - 0.5f * h;
        float x2 = cx + 0.5f * w, y2 = cy + 0.5f * h;
        float x1c = fminf(fmaxf(x1, 0.0f), W_IMGF);
        float y1c = fminf(fmaxf(y1, 0.0f), H_IMGF);
        float x2c = fminf(fmaxf(x2, 0.0f), W_IMGF);
        float y2c = fminf(fmaxf(y2, 0.0f), H_IMGF);
        int valid = ((x2c - x1c) >= MIN_SZ) && ((y2c - y1c) >= MIN_SZ);
        mx = fmaxf(fmaxf(x1c, y1c), fmaxf(x2c, y2c));
        size_t rp = (size_t)b * NSEL + r;
        boxes_r[rp * 4 + 0] = x1c; boxes_r[rp * 4 + 1] = y1c;
        boxes_r[rp * 4 + 2] = x2c; boxes_r[rp * 4 + 3] = y2c;
        score_r[rp] = score;
        size_t pp = (size_t)b * NSEL + p;
        boxes_l[pp * 4 + 0] = x1c; boxes_l[pp * 4 + 1] = y1c;
        boxes_l[pp * 4 + 2] = x2c; boxes_l[pp * 4 + 3] = y2c;
        valid_l[pp] = valid;
        rankmap[pp] = r;
    }
    // block max reduction -> single device atomic (coords >= 0: bit order == value order)
    #pragma unroll
    for (int o = 32; o > 0; o >>= 1)
        mx = fmaxf(mx, __shfl_xor(mx, o));
    if ((tid & 63) == 0) wmax[tid >> 6] = mx;
    __syncthreads();
    if (tid == 0) {
        float m2 = wmax[0];
        #pragma unroll
        for (int i = 1; i < 16; ++i) m2 = fmaxf(m2, wmax[i]);
        atomicMax(boxmax + b, __float_as_uint(m2));
    }
}

// ---------- K5: suppression bitmask (per (b,level), offset-box IoU) ----------
// mask layout: [bl][row (1024 stride)][16 u64 words]
// 256 threads/block; one 64-box column tile shared by 4 row-tiles.
__global__ void k_mask(const float* __restrict__ boxes_l, const unsigned* __restrict__ boxmax,
                       unsigned long long* __restrict__ mask) {
    int bl = blockIdx.z;
    int b = bl / NLVL, l = bl - b * NLVL;
    int kl = lvl_k(l);
    int w = blockIdx.x, rg = blockIdx.y, tid = threadIdx.x;
    if (rg * 256 >= kl) return;              // whole block beyond level rows
    float M = __uint_as_float(boxmax[b]) + 1.0f;
    float off = (float)l * M;
    __shared__ float cb[64][5];
    int j0 = w * 64;
    if (tid < 64) {
        int j = j0 + tid;
        if (j < kl) {
            const float* bp = boxes_l + ((size_t)b * NSEL + l * 1000 + j) * 4;
            float x1 = bp[0] + off, y1 = bp[1] + off, x2 = bp[2] + off, y2 = bp[3] + off;
            cb[tid][0] = x1; cb[tid][1] = y1; cb[tid][2] = x2; cb[tid][3] = y2;
            cb[tid][4] = (x2 - x1) * (y2 - y1);
        }
    }
    __syncthreads();
    int i = rg * 256 + tid;
    if (i >= kl) return;
    unsigned long long word = 0;
    if (j0 + 63 > i) {
        const float* bp = boxes_l + ((size_t)b * NSEL + l * 1000 + i) * 4;
        float ix1 = bp[0] + off, iy1 = bp[1] + off, ix2 = bp[2] + off, iy2 = bp[3] + off;
        float ai = (ix2 - ix1) * (iy2 - iy1);
        int jmax = min(64, kl - j0);
        for (int bb = 0; bb < jmax; ++bb) {
            int jj = j0 + bb;
            if (jj <= i) continue;
            float ltx = fmaxf(ix1, cb[bb][0]), lty = fmaxf(iy1, cb[bb][1]);
            float rbx = fminf(ix2, cb[bb][2]), rby = fminf(iy2, cb[bb][3]);
            float ww = fmaxf(rbx - ltx, 0.0f), hh = fmaxf(rby - lty, 0.0f);
            float inter = ww * hh;
            float iou = inter / ((ai + cb[bb][4]) - inter);   // NaN>th == false, matches jnp
            if (iou > NMS_TH) word |= (1ULL << bb);
        }
    }
    mask[((size_t)bl * 1024 + i) * 16 + w] = word;
}

// ---------- K6: sequential greedy resolve (1 wave per (b,level)) ----------
// Serial loop visits ONLY rows with nonzero within-chunk diag word
// (rem &= ballot(diag != 0)) — zero-diag rows are greedy no-ops for kw.
// Mask chunks DMA'd to LDS via global_load_lds, double-buffered.
__global__ void k_resolve(const int* __restrict__ valid_l, const int* __restrict__ rankmap,
                          const unsigned long long* __restrict__ mask, int* __restrict__ keep_r) {
    const int bl = blockIdx.x;
    const int b = bl / NLVL, l = bl - b * NLVL;
    const int kl = lvl_k(l);
    const int lane = threadIdx.x;     // 64 threads = 1 wave
    __shared__ __align__(16) unsigned long long sbufA[64 * 16];  // 8 KB, mirror layout
    __shared__ __align__(16) unsigned long long sbufB[64 * 16];  // 8 KB
    const int base = b * NSEL + l * 1000;

    // keep word per chunk, distributed: lane w (w<16) holds chunk w's keep bits
    unsigned long long keep_w = 0;
    for (int c = 0; c < 16; ++c) {
        int q = c * 64 + lane;
        int vv = (q < kl) ? valid_l[base + q] : 0;
        unsigned long long bm = __ballot(vv);
        if (lane == c) keep_w = bm;
    }

    const int nch = (kl + 63) >> 6;   // 16 or 12
    const char* mbyte = (const char*)(mask + (size_t)bl * 1024 * 16);

    // DMA chunk 0 -> sbufA (8 x 1KB instructions; lane scatters 16B each)
    {
        const char* g0 = mbyte + (size_t)lane * 16;
        #pragma unroll
        for (int j = 0; j < 8; ++j)
            async_cp16(g0 + j * 1024, (char*)sbufA + j * 1024);
    }

    for (int c = 0; c < nch; ++c) {
        unsigned long long* cur = (c & 1) ? sbufB : sbufA;
        unsigned long long* nxt = (c & 1) ? sbufA : sbufB;
        __syncthreads();                       // drains vmcnt: chunk c staged
        if (c + 1 < nch) {
            const char* g1 = mbyte + (size_t)(c + 1) * 8192 + (size_t)lane * 16;
            #pragma unroll
            for (int j = 0; j < 8; ++j)
                async_cp16(g1 + j * 1024, (char*)nxt + j * 1024);
        }
        unsigned long long kw = __shfl(keep_w, c);   // uniform
        if (kw) {
            // diagonal word (word c of this lane's row): one conflicted read/chunk
            unsigned long long diag = cur[lane * 16 + c];
            unsigned dlo = (unsigned)diag, dhi = (unsigned)(diag >> 32);
            // rows with zero diag suppress nothing in-chunk: skip them wholesale
            unsigned long long nz = __ballot(diag != 0ULL);
            unsigned long long rem = kw & nz;
            while (rem) {
                int r = __ffsll((long long)rem) - 1;
                unsigned lo = __builtin_amdgcn_readlane(dlo, r);
                unsigned hi = __builtin_amdgcn_readlane(dhi, r);
                unsigned long long d = ((unsigned long long)hi << 32) | lo;
                kw &= ~d;
                rem &= ~(d | (1ULL << r));
            }
            // batched cross-chunk suppression: lane w<16 ORs word w of kept rows
            unsigned long long supp = 0;
            if (lane < 16) {
                #pragma unroll
                for (int r = 0; r < 64; ++r) {
                    unsigned long long m = cur[r * 16 + lane];
                    supp |= (((kw >> r) & 1ULL) ? m : 0ULL);
                }
            }
            if (lane == c) keep_w = kw;
            else if (lane < 16 && lane > c) keep_w &= ~supp;
        }
    }
    __syncthreads();
    // scatter keep bits to global-rank order
    for (int c = 0; c < 16; ++c) {
        unsigned long long kwc = __shfl(keep_w, c);
        int q = c * 64 + lane;
        if (q < kl)
            keep_r[b * NSEL + rankmap[base + q]] = (int)((kwc >> lane) & 1ULL);
    }
}

// ---------- K7: compact kept entries (score order) into output ----------
// 1024 threads, CH=5 — short serial count/scatter tails per thread.
__global__ void k_output(const int* __restrict__ keep_r, const float* __restrict__ boxes_r,
                         const float* __restrict__ score_r, float* __restrict__ out) {
    int b = blockIdx.x, tid = threadIdx.x;    // 1024
    float* ob = out + (size_t)b * POST_NMS * 4;
    float* osc = out + (size_t)B_IMGS * POST_NMS * 4 + (size_t)b * POST_NMS;
    for (int p = tid; p < POST_NMS; p += 1024) {
        ob[p * 4 + 0] = 0.0f; ob[p * 4 + 1] = 0.0f;
        ob[p * 4 + 2] = 0.0f; ob[p * 4 + 3] = 0.0f;
        osc[p] = NEGV;
    }
    __syncthreads();   // global writes drained before barrier (vmcnt)
    const int CH = 5;  // 5*1024 = 5120 >= 4741
    int base = tid * CH;
    int cnt = 0;
    #pragma unroll
    for (int k = 0; k < CH; ++k) {
        int r = base + k;
        if (r < NSEL) cnt += keep_r[b * NSEL + r];
    }
    __shared__ int ps[1024];
    ps[tid] = cnt;
    __syncthreads();
    for (int ofs = 1; ofs < 1024; ofs <<= 1) {
        int v = (tid >= ofs) ? ps[tid - ofs] : 0;
        __syncthreads();
        ps[tid] += v;
        __syncthreads();
    }
    int p = ps[tid] - cnt;   // exclusive prefix
    #pragma unroll
    for (int k = 0; k < CH; ++k) {
        int r = base + k;
        if (r < NSEL && keep_r[b * NSEL + r]) {
            if (p < POST_NMS) {
                const float* bp = boxes_r + ((size_t)b * NSEL + r) * 4;
                ob[p * 4 + 0] = bp[0]; ob[p * 4 + 1] = bp[1];
                ob[p * 4 + 2] = bp[2]; ob[p * 4 + 3] = bp[3];
                osc[p] = score_r[(size_t)b * NSEL + r];
            }
            ++p;
        }
    }
}

extern "C" void kernel_launch(void* const* d_in, const int* in_sizes, int n_in,
                              void* d_out, int out_size, void* d_ws, size_t ws_size,
                              hipStream_t stream) {
    const float* obj     = (const float*)d_in[0];   // [4, 242991]
    const float* deltas  = (const float*)d_in[1];   // [4, 242991, 4]
    const float* anchors = (const float*)d_in[2];   // [242991, 4]
    float* out = (float*)d_out;                     // [4,1000,4] ++ [4,1000]

    char* ws = (char*)d_ws;
    unsigned*            hist    = (unsigned*)(ws);
    unsigned*            cnt     = (unsigned*)(ws + OFF_CNT);
    unsigned*            boxmax  = (unsigned*)(ws + OFF_BOXMAX);
    unsigned long long*  cand    = (unsigned long long*)(ws + OFF_CAND);
    unsigned long long*  sel     = (unsigned long long*)(ws + OFF_SEL);
    float*               boxes_r = (float*)(ws + OFF_BOXR);
    float*               score_r = (float*)(ws + OFF_SCR);
    float*               boxes_l = (float*)(ws + OFF_BOXL);
    int*                 valid_l = (int*)(ws + OFF_VAL);
    int*                 rankmap = (int*)(ws + OFF_RMAP);
    int*                 keep_r  = (int*)(ws + OFF_KEEP);
    unsigned long long*  maskp   = (unsigned long long*)(ws + OFF_MASK);

    (void)in_sizes; (void)n_in; (void)out_size; (void)ws_size; (void)WS_NEED;

    // zero hist + cnt + boxmax (ws is poisoned 0xAA before every call)
    hipMemsetAsync(d_ws, 0, ZERO_BYTES, stream);

    k_hist<<<B_IMGS * HBLK_PER_IMG, 512, 0, stream>>>(obj, hist);
    k_compact<<<B_IMGS * CBLK_PER_IMG, 256, 0, stream>>>(obj, hist, cnt, cand);
    k_sortlevel<<<NBL, 1024, 0, stream>>>(cand, cnt, sel);
    k_decode<<<dim3(5, B_IMGS), 1024, 0, stream>>>(
        deltas, anchors, sel, boxes_r, score_r, boxes_l, valid_l, rankmap, boxmax);
    k_mask<<<dim3(16, 4, NBL), 256, 0, stream>>>(boxes_l, boxmax, maskp);
    k_resolve<<<NBL, 64, 0, stream>>>(valid_l, rankmap, maskp, keep_r);
    k_output<<<B_IMGS, 1024, 0, stream>>>(keep_r, boxes_r, score_r, out);
}